// Round 13
// baseline (374.526 us; speedup 1.0000x reference)
//
#include <hip/hip_runtime.h>
#include <hip/hip_bf16.h>
#include <cstdint>

// Problem constants (fixed by reference)
#define NN 100000
#define HH 96
#define AD 32
#define DE 16
#define EE 500000
#define NEG 0.01f

// Bucketing: 196 buckets of 512 nodes per edge type
#define GSH 9
#define GSZ 512
#define KB 196
#define CH 2048
#define BPT 245          // ceil(EE/CH)
#define PCAP 801056      // EE + 3*GSZ*KB  (padded record capacity per type)

// setup_kernel block-range split
#define PREP_B 128
#define CAST_B 12500
#define HIST_B 512

typedef __bf16 bf16x8 __attribute__((ext_vector_type(8)));
typedef float  f32x4  __attribute__((ext_vector_type(4)));
typedef unsigned long long ull;
typedef unsigned long long ull2 __attribute__((ext_vector_type(2)));

__device__ __forceinline__ unsigned short f2b(float x) {
    union { float f; unsigned int u; } v; v.f = x;
    unsigned int r = v.u + 0x7fffu + ((v.u >> 16) & 1u);  // RNE
    return (unsigned short)(r >> 16);
}
__device__ __forceinline__ float b2f(unsigned short h) {
    union { unsigned int u; float f; } v; v.u = ((unsigned int)h) << 16;
    return v.f;
}

// ---------------------------------------------------------------------------
// Algebraic fusion of the two GEMMs (weights folded at prep):
//   out = relu( h @ B' + sum_t hagg_t @ A_t + bias' )
//   A_t  = WmS_t @ WuT_t              (rows 96+96t of F)
//   B'   = WuH + sum_t WmD_t @ WuT_t  (rows 0..95 of F)
//   bias'= bu + sum_t cb_t,  cb_t = cvec_t @ WuT_t
// Rows with den_t==0 are corrected IN-REGISTER inside fused_out (subtract
// h@D_t + cb_t for each zero type; D_t = WmD_t @ WuT_t, f32) before relu.
//
// setup_kernel: three independent phases in ONE launch (launch-count
// minimization: 7 dispatches total per iteration):
//   blocks [0, PREP_B):             folded-weight prep (BfF / Dmat / cb)
//   blocks [PREP_B, +CAST_B):       bf16 cast of h + u/v attention pre-dots
//                                   (wvec table computed per-block in LDS)
//   blocks [PREP_B+CAST_B, +HIST_B) per-bucket edge histogram (bCnt
//                                   pre-zeroed by hipMemsetAsync)
// BfF: 12 ksteps x 6 colblocks x 64 lanes x 8 (F is 384x96, stacked
//      [B' | A_0 | A_1 | A_2]); B-frag: lane=((k%32)/8)*16+(n%16), j=k%8
// ---------------------------------------------------------------------------
__global__ __launch_bounds__(256) void setup_kernel(
    const float* __restrict__ h,
    const float* Wm0, const float* bm0, const float* ef0,
    const float* Wm1, const float* bm1, const float* ef1,
    const float* Wm2, const float* bm2, const float* ef2,
    const float* Wn0, const float* Wa0,
    const float* Wn1, const float* Wa1,
    const float* Wu,
    const int* __restrict__ d0, const int* __restrict__ d1,
    const int* __restrict__ d2,
    unsigned short* BfF, float* Dmat, float* cb,
    unsigned short* __restrict__ hb, float* __restrict__ uv,
    int* __restrict__ bCnt) {
    __shared__ int hist[3 * KB];
    __shared__ float wv[384];
    int bid = blockIdx.x;
    int t = threadIdx.x;
    if (bid < PREP_B) {
        // ---- phase P: folded-weight prep ----
        const float* Wm[3] = {Wm0, Wm1, Wm2};
        const float* bm[3] = {bm0, bm1, bm2};
        const float* ef[3] = {ef0, ef1, ef2};
        const int T_BFF = 36864, T_D = 27648, T_CB = 288;
        const int total = T_BFF + T_D + T_CB;
        for (int i = bid * 256 + t; i < total; i += PREP_B * 256) {
            if (i < T_BFF) {
                int ksc = i / 512, lj = i % 512;
                int ks = ksc / 6, c = ksc % 6;
                int lane = lj / 8, jj = lj % 8;
                int quad = lane / 16, m = lane % 16;
                int k = ks * 32 + quad * 8 + jj;   // 0..383 (row of F)
                int n = c * 16 + m;
                float s;
                if (k < 96) {
                    s = Wu[k * HH + n];
                    for (int tt = 0; tt < 3; ++tt) {
                        const float* wm = Wm[tt];
                        float a = 0.f;
                        for (int j = 0; j < 96; ++j)
                            a += wm[(96 + k) * HH + j] * Wu[(96 + 96 * tt + j) * HH + n];
                        s += a;
                    }
                } else {
                    int tt = (k - 96) / 96, kk = (k - 96) % 96;
                    const float* wm = Wm[tt];
                    s = 0.f;
                    for (int j = 0; j < 96; ++j)
                        s += wm[kk * HH + j] * Wu[(96 + 96 * tt + j) * HH + n];
                }
                BfF[i] = f2b(s);
            } else if (i < T_BFF + T_D) {
                int ii = i - T_BFF;
                int tt = ii / 9216, r = ii % 9216;
                int k = r / 96, n = r % 96;
                const float* wm = Wm[tt];
                float s = 0.f;
                for (int j = 0; j < 96; ++j)
                    s += wm[(96 + k) * HH + j] * Wu[(96 + 96 * tt + j) * HH + n];
                Dmat[ii] = s;
            } else {
                int ii = i - T_BFF - T_D;
                int tt = ii / 96, n = ii % 96;
                const float* wm = Wm[tt];
                float s = 0.f;
                for (int k = 0; k < 96; ++k) {
                    float cv = bm[tt][k];
                    for (int j = 0; j < DE; ++j)
                        cv += ef[tt][j] * wm[(192 + j) * HH + k];
                    s += cv * Wu[(96 + 96 * tt + k) * HH + n];
                }
                cb[ii] = s;
            }
        }
    } else if (bid < PREP_B + CAST_B) {
        // ---- phase C: bf16 cast + u/v pre-dots (one 32-lane group/node).
        // wvec table (384 f32) computed per-block in LDS: <=2 length-32
        // dots per thread, inputs L1/L2-resident. No cross-kernel dep.
        for (int ii = t; ii < 384; ii += 256) {
            int kind = ii / 96, kk = ii % 96;
            const float* Wn = (kind < 2) ? Wn0 : Wn1;
            const float* Wa = (kind < 2) ? Wa0 : Wa1;
            int off = (kind & 1) ? AD : 0;
            float s = 0.f;
            for (int a = 0; a < AD; ++a) s += Wn[kk * AD + a] * Wa[off + a];
            wv[ii] = s;
        }
        __syncthreads();
        int lane = t & 31;
        int node = (((bid - PREP_B) * 256 + t) >> 5);   // < NN by construction
        float h0 = h[node * HH + lane];
        float h1 = h[node * HH + 32 + lane];
        float h2 = h[node * HH + 64 + lane];
        hb[node * HH + lane] = f2b(h0);
        hb[node * HH + 32 + lane] = f2b(h1);
        hb[node * HH + 64 + lane] = f2b(h2);
        float acc[4];
#pragma unroll
        for (int q = 0; q < 4; ++q)
            acc[q] = h0 * wv[q * 96 + lane] + h1 * wv[q * 96 + 32 + lane] +
                     h2 * wv[q * 96 + 64 + lane];
#pragma unroll
        for (int d = 16; d >= 1; d >>= 1)
#pragma unroll
            for (int q = 0; q < 4; ++q) acc[q] += __shfl_down(acc[q], d, 32);
        if (lane == 0) {
#pragma unroll
            for (int q = 0; q < 4; ++q) uv[q * NN + node] = acc[q];
        }
    } else {
        // ---- phase H: bucket histogram ----
        int hb_ = bid - (PREP_B + CAST_B);
        for (int j = t; j < 3 * KB; j += 256) hist[j] = 0;
        __syncthreads();
        const int total = 3 * EE;
        for (int i = hb_ * 256 + t; i < total; i += HIST_B * 256) {
            int ty = i / EE, e = i - ty * EE;
            const int* d = (ty == 0) ? d0 : (ty == 1) ? d1 : d2;
            atomicAdd(&hist[ty * KB + (d[e] >> GSH)], 1);
        }
        __syncthreads();
        for (int j = t; j < 3 * KB; j += 256)
            if (hist[j]) atomicAdd(&bCnt[j], hist[j]);
    }
}

// ---------------------------------------------------------------------------
// Two-level CSR build (round-8 verified): scan -> LDS-ranked scatter (u32
// recs, line-dense writes) -> per-bucket counting sort. The sort pads each
// node's list to x4 with zero-weight records, computes the edge attention
// weight ONCE per edge, emits wrec = {w:f32 | src*192} and rse =
// {padded_cnt | start}. Natural node order kept (round-10 lesson: wrec list
// contiguity beats divergence sorting).
// ---------------------------------------------------------------------------
__global__ void bucket_scan(const int* __restrict__ bCnt, int* __restrict__ bBase,
                            int* __restrict__ gCursor) {
    __shared__ int hist[3 * KB];
    int t = threadIdx.x;
    if (t < 3 * KB) hist[t] = bCnt[t];
    __syncthreads();
    if (t < 3) {
        int run = 0;
        for (int b = 0; b < KB; ++b) {
            bBase[t * (KB + 1) + b] = run;
            gCursor[t * KB + b] = run;
            run += hist[t * KB + b];
        }
        bBase[t * (KB + 1) + KB] = run;           // == EE
    }
}

__global__ __launch_bounds__(256) void bucket_scatter(
    const int* __restrict__ s0, const int* __restrict__ d0,
    const int* __restrict__ s1, const int* __restrict__ d1,
    const int* __restrict__ s2, const int* __restrict__ d2,
    int* __restrict__ gCursor, unsigned int* __restrict__ binned) {
    __shared__ unsigned int recs[CH];
    __shared__ unsigned short rnk[CH];
    __shared__ unsigned char bkt[CH];
    __shared__ int cnt[KB];
    __shared__ int gpos[KB];
    int t = threadIdx.x;
    int type = blockIdx.x / BPT;
    int chunk = (blockIdx.x % BPT) * CH;
    const int* src = (type == 0) ? s0 : (type == 1) ? s1 : s2;
    const int* dst = (type == 0) ? d0 : (type == 1) ? d1 : d2;
    if (t < KB) cnt[t] = 0;
    __syncthreads();
#pragma unroll
    for (int k = 0; k < CH / 256; ++k) {
        int idx = k * 256 + t;
        int e = chunk + idx;
        if (e < EE) {
            int s = src[e], d = dst[e];
            int b = d >> GSH;
            recs[idx] = ((unsigned int)s << GSH) | (unsigned int)(d & (GSZ - 1));
            bkt[idx] = (unsigned char)b;
            rnk[idx] = (unsigned short)atomicAdd(&cnt[b], 1);
        } else {
            bkt[idx] = 0xFF;
        }
    }
    __syncthreads();
    if (t < KB) {
        int c = cnt[t];
        gpos[t] = (c > 0) ? atomicAdd(&gCursor[type * KB + t], c) : 0;
    }
    __syncthreads();
    unsigned int* bout = binned + (size_t)type * EE;
#pragma unroll
    for (int k = 0; k < CH / 256; ++k) {
        int idx = k * 256 + t;
        unsigned char b = bkt[idx];
        if (b != 0xFF) bout[gpos[b] + rnk[idx]] = recs[idx];
    }
}

__global__ __launch_bounds__(256) void bucket_sort(
    const unsigned int* __restrict__ binned, const int* __restrict__ bBase,
    const float* __restrict__ uv,
    ull* __restrict__ rse, ull* __restrict__ wrec) {
    __shared__ int cnt[GSZ];
    __shared__ float vbuf[GSZ];
    __shared__ int wsum[4];
    int t = threadIdx.x;
    int type = blockIdx.x / KB;
    int b = blockIdx.x % KB;
    int nodeBase = b * GSZ;
    int eb = bBase[type * (KB + 1) + b];
    int en = bBase[type * (KB + 1) + b + 1];
    int n = en - eb;
    int pbase = eb + 3 * GSZ * b;   // padded bucket base (slack 3*GSZ/bucket)
    const unsigned int* bin = binned + (size_t)type * EE + eb;
    cnt[t] = 0;
    cnt[t + 256] = 0;
    if (type < 2) {
        const float* vsrc = uv + (2 * type + 1) * NN;
        int nd0 = nodeBase + t, nd1 = nodeBase + 256 + t;
        vbuf[t] = (nd0 < NN) ? vsrc[nd0] : 0.f;
        vbuf[t + 256] = (nd1 < NN) ? vsrc[nd1] : 0.f;
    }
    __syncthreads();
    for (int i = t; i < n; i += 256) atomicAdd(&cnt[bin[i] & (GSZ - 1)], 1);
    __syncthreads();
    // thread t owns nodes 2t and 2t+1 of this bucket
    int v0 = cnt[t * 2], v1 = cnt[t * 2 + 1];
    int p0 = (v0 + 3) & ~3, p1 = (v1 + 3) & ~3;
    int s = p0 + p1;
    // wave-shuffle inclusive scan over 256 threads (1 barrier, not 16)
    int lane = t & 63, wv = t >> 6;
    int val = s;
#pragma unroll
    for (int d = 1; d < 64; d <<= 1) {
        int o = __shfl_up(val, d, 64);
        if (lane >= d) val += o;
    }
    if (lane == 63) wsum[wv] = val;
    __syncthreads();
    int wpre = 0;
#pragma unroll
    for (int i = 0; i < 4; ++i) wpre += (i < wv) ? wsum[i] : 0;
    int excl = val - s + wpre;   // exclusive padded base among this bucket's nodes
    int off0 = excl, off1 = excl + p0;
    ull* wb = wrec + (size_t)type * PCAP;
    int node0 = nodeBase + t * 2, node1 = nodeBase + t * 2 + 1;
    if (node0 < NN) {
        rse[(size_t)type * NN + node0] =
            ((ull)(unsigned int)p0 << 32) | (unsigned int)(pbase + off0);
        for (int q = v0; q < p0; ++q) wb[pbase + off0 + q] = 0ull;
    }
    if (node1 < NN) {
        rse[(size_t)type * NN + node1] =
            ((ull)(unsigned int)p1 << 32) | (unsigned int)(pbase + off1);
        for (int q = v1; q < p1; ++q) wb[pbase + off1 + q] = 0ull;
    }
    __syncthreads();  // all cnt reads done before overwrite
    cnt[t * 2] = off0;
    cnt[t * 2 + 1] = off1;
    __syncthreads();
    const float* usrc = uv + 2 * type * NN;
    for (int i = t; i < n; i += 256) {
        unsigned int r = bin[i];
        int dl = r & (GSZ - 1);
        int p = atomicAdd(&cnt[dl], 1);
        unsigned int sidx = r >> GSH;
        float w = 1.f;
        if (type < 2) {
            float c = usrc[sidx] + vbuf[dl];
            c = fmaxf(c, NEG * c);  // leaky_relu
            w = __expf(c);
        }
        wb[pbase + p] = ((ull)__float_as_uint(w) << 32) | (ull)(sidx * 192u);
    }
}

// All-type h-space gather aggregation in ONE launch: grid (12500, 3).
// Round-8-verified form (62us, FETCH 165MB). Natural node order; lists
// padded to x4 with zero-weight records: no conditionals in the loop,
// 32B-aligned record loads (group-uniform -> HW broadcast). Lane l owns
// columns {2l, 2l+1, 64+l}: one dword + one ushort load per edge.
__global__ void aggregate_kernel(const ull* __restrict__ rse,
                                 const ull* __restrict__ wrec,
                                 const unsigned short* __restrict__ hb,
                                 unsigned short* __restrict__ hagg,
                                 float* __restrict__ den) {
    const size_t NH = (size_t)NN * HH;
    int lane = threadIdx.x & 31;
    int node = (blockIdx.x * blockDim.x + threadIdx.x) >> 5;
    if (node >= NN) return;
    int t = blockIdx.y;
    ull se = rse[(size_t)t * NN + node];
    int beg = (int)(unsigned int)se;
    int end = beg + (int)(se >> 32);
    const ull* wr = wrec + (size_t)t * PCAP;
    float a0 = 0.f, a1 = 0.f, a2 = 0.f, dn = 0.f;
    const char* b0 = (const char*)hb + 4 * lane;        // cols 2l,2l+1 (dword)
    const char* b1 = (const char*)hb + 128 + 2 * lane;  // col 64+l (ushort)
#define EDGE(rec)                                                              \
    {                                                                          \
        float w = __uint_as_float((unsigned int)((rec) >> 32));                \
        unsigned int off = (unsigned int)(rec);                                \
        unsigned int dv = *(const unsigned int*)(b0 + off);                    \
        unsigned int sv = *(const unsigned short*)(b1 + off);                  \
        a0 += w * __uint_as_float(dv << 16);                                   \
        a1 += w * __uint_as_float(dv & 0xFFFF0000u);                           \
        a2 += w * __uint_as_float(sv << 16);                                   \
        dn += w;                                                               \
    }
    for (int j = beg; j < end; j += 4) {
        ull2 p0 = *(const ull2*)(wr + j);
        ull2 p1 = *(const ull2*)(wr + j + 2);
        EDGE(p0[0]);
        EDGE(p0[1]);
        EDGE(p1[0]);
        EDGE(p1[1]);
    }
#undef EDGE
    float inv = (dn > 0.f) ? 1.f / dn : 0.f;
    float q0 = a0 * inv, q1 = a1 * inv, q2 = a2 * inv;
    char* mr = (char*)(hagg + (size_t)t * NH + (size_t)node * HH);
    *(unsigned int*)(mr + 4 * lane) =
        (unsigned int)f2b(q0) | ((unsigned int)f2b(q1) << 16);
    *(unsigned short*)(mr + 128 + 2 * lane) = f2b(q2);
    if (lane == 0) den[(size_t)t * NN + node] = dn;
}

// Fused output GEMM: out = relu(h@B' + sum_t hagg_t@A_t + bias'), K=384
// MFMA. Dirty rows (any den_t==0, ~2% of rows) are corrected IN-REGISTER:
// subtract (h_row @ D_t + cb_t) for each zero type before the relu store.
// All 16 lanes holding a given row share the branch (quad-uniform); ~28%
// of waves take a ~600-cycle slow path — cheaper than a separate fixup
// launch + full-NN den rescan. Grid 1563 x 4 waves, 16 rows/wave.
__global__ __launch_bounds__(256) void fused_out_kernel(
    const unsigned short* __restrict__ hagg,
    const unsigned short* __restrict__ hb,
    const unsigned short* __restrict__ BfF,
    const float* __restrict__ den,
    const float* __restrict__ Dmat,
    const float* __restrict__ cb,
    const float* __restrict__ bu,
    float* __restrict__ out) {
    const size_t NH = (size_t)NN * HH;
    int wave = threadIdx.x >> 6;
    int lane = threadIdx.x & 63;
    int quad = lane >> 4, m = lane & 15;
    int blk = blockIdx.x * 4 + wave;
    if (blk >= NN / 16) return;
    int r0 = blk * 16;
    f32x4 acc[6] = {};
#pragma unroll
    for (int ks = 0; ks < 12; ++ks) {
        const unsigned short* ap =
            (ks < 3) ? hb + (size_t)(r0 + m) * HH + ks * 32 + quad * 8
                     : hagg + (size_t)((ks - 3) / 3) * NH + (size_t)(r0 + m) * HH +
                           ((ks - 3) % 3) * 32 + quad * 8;
        bf16x8 af = *(const bf16x8*)ap;
#pragma unroll
        for (int c = 0; c < 6; ++c) {
            bf16x8 bfv = *(const bf16x8*)(BfF + ((ks * 6 + c) << 9) + lane * 8);
            acc[c] = __builtin_amdgcn_mfma_f32_16x16x32_bf16(af, bfv, acc[c], 0, 0, 0);
        }
    }
    float dn0[4], dn1[4], dn2[4];
#pragma unroll
    for (int r = 0; r < 4; ++r) {
        int row = r0 + quad * 4 + r;
        dn0[r] = den[row];
        dn1[r] = den[NN + row];
        dn2[r] = den[2 * NN + row];
    }
    // in-register dirty-row correction (rare; quad-uniform branch)
#pragma unroll
    for (int r = 0; r < 4; ++r) {
        bool z0 = !(dn0[r] > 0.f), z1 = !(dn1[r] > 0.f), z2 = !(dn2[r] > 0.f);
        if (z0 | z1 | z2) {
            int row = r0 + quad * 4 + r;
            const unsigned short* hr = hb + (size_t)row * HH;
#pragma unroll 1
            for (int tt = 0; tt < 3; ++tt) {
                bool z = (tt == 0) ? z0 : (tt == 1) ? z1 : z2;
                if (!z) continue;
                const float* D = Dmat + tt * 9216;
                float corr[6];
#pragma unroll
                for (int c = 0; c < 6; ++c) corr[c] = cb[tt * 96 + c * 16 + m];
                for (int k = 0; k < 96; ++k) {
                    float hv = b2f(hr[k]);
#pragma unroll
                    for (int c = 0; c < 6; ++c) corr[c] += hv * D[k * 96 + c * 16 + m];
                }
#pragma unroll
                for (int c = 0; c < 6; ++c) acc[c][r] -= corr[c];
            }
        }
    }
#pragma unroll
    for (int c = 0; c < 6; ++c) {
        int n = c * 16 + m;
        float bias = bu[n] + cb[n] + cb[96 + n] + cb[192 + n];
#pragma unroll
        for (int r = 0; r < 4; ++r) {
            int row = r0 + quad * 4 + r;
            float v = acc[c][r] + bias;
            out[(size_t)row * HH + n] = v > 0.f ? v : 0.f;
        }
    }
}

extern "C" void kernel_launch(void* const* d_in, const int* in_sizes, int n_in,
                              void* d_out, int out_size, void* d_ws, size_t ws_size,
                              hipStream_t stream) {
    (void)in_sizes; (void)n_in; (void)out_size;
    const float* h   = (const float*)d_in[0];
    const int* srcs[3] = {(const int*)d_in[1], (const int*)d_in[3], (const int*)d_in[5]};
    const int* dsts[3] = {(const int*)d_in[2], (const int*)d_in[4], (const int*)d_in[6]};
    const float* Wm0 = (const float*)d_in[7];
    const float* bm0 = (const float*)d_in[8];
    const float* ef0 = (const float*)d_in[9];
    const float* Wm1 = (const float*)d_in[10];
    const float* bm1 = (const float*)d_in[11];
    const float* ef1 = (const float*)d_in[12];
    const float* Wm2 = (const float*)d_in[13];
    const float* bm2 = (const float*)d_in[14];
    const float* ef2 = (const float*)d_in[15];
    const float* Wn0 = (const float*)d_in[16];
    const float* Wa0 = (const float*)d_in[17];
    const float* Wn1 = (const float*)d_in[18];
    const float* Wa1 = (const float*)d_in[19];
    const float* Wu  = (const float*)d_in[20];
    const float* bu  = (const float*)d_in[21];
    float* out = (float*)d_out;

    // Workspace layout (same offsets as round 12; wvec slot unused).
    const size_t NEED = 107419648;
    if (ws_size < NEED) return;  // fail validation cleanly instead of faulting
    char* w = (char*)d_ws;
    unsigned short* hb      = (unsigned short*)(w + 0);            // N*96 bf16   -> 19,200,000
    unsigned short* hagg    = (unsigned short*)(w + 19200000);     // 3*N*96 bf16 -> 76,800,000
    float*          den     = (float*)(w + 76800000);              // 3*N f32     -> 78,000,000
    float*          uv      = (float*)(w + 78000000);              // 4*N f32     -> 79,600,000
    unsigned short* BfF     = (unsigned short*)(w + 79601536);     // 36864 bf16  -> 79,675,264
    float*          Dmat    = (float*)(w + 79675264);              // 3*9216 f32  -> 79,785,856
    float*          cb      = (float*)(w + 79785856);              // 288 f32     -> 79,787,008
    int*            bBase   = (int*)(w + 79787008);                // 2432B slot  -> 79,789,440
    int*            gCursor = (int*)(w + 79789440);                // 2432B slot  -> 79,791,872
    int*            bCnt    = (int*)(w + 79791872);                // 2432B slot  -> 79,794,304
    ull*            rse     = (ull*)(w + 79794304);                // 3*N u64     -> 82,194,304
    unsigned int*   binned  = (unsigned int*)(w + 82194304);       // 3*E u32     -> 88,194,304
    ull*            wrec    = (ull*)(w + 88194304);                // 3*PCAP u64  -> 107,419,648

    hipMemsetAsync(bCnt, 0, 3 * KB * sizeof(int), stream);
    setup_kernel<<<PREP_B + CAST_B + HIST_B, 256, 0, stream>>>(
        h, Wm0, bm0, ef0, Wm1, bm1, ef1, Wm2, bm2, ef2,
        Wn0, Wa0, Wn1, Wa1, Wu,
        dsts[0], dsts[1], dsts[2], BfF, Dmat, cb, hb, uv, bCnt);
    bucket_scan<<<1, 640, 0, stream>>>(bCnt, bBase, gCursor);
    bucket_scatter<<<3 * BPT, 256, 0, stream>>>(srcs[0], dsts[0], srcs[1], dsts[1],
                                                srcs[2], dsts[2], gCursor, binned);
    bucket_sort<<<3 * KB, 256, 0, stream>>>(binned, bBase, uv, rse, wrec);

    aggregate_kernel<<<dim3(12500, 3), 256, 0, stream>>>(rse, wrec, hb, hagg, den);
    fused_out_kernel<<<1563, 256, 0, stream>>>(hagg, hb, BfF, den, Dmat, cb, bu, out);
}